// Round 1
// 903.260 us; speedup vs baseline: 1.6654x; 1.6654x over previous
//
#include <hip/hip_runtime.h>
#include <hip/hip_bf16.h>

typedef __hip_bfloat16 bf16;
typedef __attribute__((ext_vector_type(8))) short bf16x8;  // 8 bf16 in 4 VGPRs
typedef __attribute__((ext_vector_type(4))) float f32x4;

// ---------------- bf16 split helpers (Ootomo bf16x3 scheme) ----------------

__device__ __forceinline__ short f2bf(float x) {  // RNE float->bf16 bits
    unsigned u = __float_as_uint(x);
    unsigned r = (u + 0x7FFFu + ((u >> 16) & 1u)) >> 16;
    return (short)r;
}
__device__ __forceinline__ float bf2f(short s) {
    return __uint_as_float(((unsigned)(unsigned short)s) << 16);
}

// Load 8 consecutive floats (16B-aligned), split into hi/lo bf16 fragments.
__device__ __forceinline__ void split8(const float* __restrict__ p, bool ok, bf16x8& hi,
                                       bf16x8& lo) {
    float v[8];
    if (ok) {
        float4 x0 = ((const float4*)p)[0];
        float4 x1 = ((const float4*)p)[1];
        v[0] = x0.x; v[1] = x0.y; v[2] = x0.z; v[3] = x0.w;
        v[4] = x1.x; v[5] = x1.y; v[6] = x1.z; v[7] = x1.w;
    } else {
#pragma unroll
        for (int j = 0; j < 8; j++) v[j] = 0.f;
    }
#pragma unroll
    for (int j = 0; j < 8; j++) {
        short hb = f2bf(v[j]);
        hi[j] = hb;
        lo[j] = f2bf(v[j] - bf2f(hb));
    }
}

// ---------------- dtype forensics (masks / indices) ----------------
// modes: 0=u8/bool, 1=int32, 2=float32, 3=int64, 4=float64
__global__ __launch_bounds__(256) void forensic_kernel(const unsigned int* __restrict__ mask_w,
                                                       const unsigned int* __restrict__ idx_w,
                                                       int nw_mask, int nw_idx,
                                                       int* __restrict__ flags) {
    __shared__ int sm[6];
    int t = threadIdx.x;
    if (t < 6) sm[t] = 0;
    __syncthreads();
    int m_gt1 = 0, m_f32 = 0, m_f64 = 0, m_oddnz = 0, i_hi = 0, i_oddnz = 0;
    for (int i = t; i < nw_mask; i += 256) {
        unsigned int w = mask_w[i];
        if (w > 1u && w != 0x3F800000u && w != 0x3FF00000u) m_gt1++;
        if (w == 0x3F800000u) m_f32++;
        if ((i & 1) && w == 0x3FF00000u) m_f64++;
        if ((i & 1) && w != 0u) m_oddnz++;
    }
    for (int i = t; i < nw_idx; i += 256) {
        unsigned int v = idx_w[i];
        if (v >= 0x20000000u) i_hi++;
        if ((i & 1) && v != 0u) i_oddnz++;
    }
    atomicAdd(&sm[0], m_gt1);
    atomicAdd(&sm[1], m_f32);
    atomicAdd(&sm[2], m_f64);
    atomicAdd(&sm[3], m_oddnz);
    atomicAdd(&sm[4], i_hi);
    atomicAdd(&sm[5], i_oddnz);
    __syncthreads();
    if (t == 0) {
        int mmode;
        if (sm[1] > 50) mmode = 2;
        else if (sm[2] > 50) mmode = 4;
        else if (sm[0] > 50) mmode = 0;
        else if (sm[3] > 50) mmode = 1;
        else mmode = 3;
        int imode;
        if (sm[4] > (nw_idx * 3) / 4) imode = 2;
        else if (sm[4] > nw_idx / 4) imode = 4;
        else if (sm[5] > 50) imode = 1;
        else imode = 3;
        flags[0] = mmode;
        flags[1] = imode;
    }
}

__device__ __forceinline__ int fetch_idx(const void* p, int e, int mode) {
    switch (mode) {
        case 1: return ((const int*)p)[e];
        case 3: return (int)(((const long long*)p)[e]);
        case 2: return (int)(((const float*)p)[e]);
        default: return (int)(((const double*)p)[e]);
    }
}

__global__ __launch_bounds__(256) void conv_mask_kernel(const void* __restrict__ m,
                                                        const int* __restrict__ flags, int n,
                                                        unsigned char* __restrict__ out) {
    int mode = flags[0];
    int i = blockIdx.x * 256 + threadIdx.x;
    if (i >= n) return;
    bool v;
    switch (mode) {
        case 0: v = ((const unsigned char*)m)[i] != 0; break;
        case 1: v = ((const int*)m)[i] != 0; break;
        case 2: v = ((const float*)m)[i] != 0.f; break;
        case 3: v = ((const long long*)m)[i] != 0; break;
        default: v = ((const double*)m)[i] != 0.0; break;
    }
    out[i] = v ? 1 : 0;
}

// ---------------- CSR build ----------------

__global__ __launch_bounds__(256) void hist_kernel(const void* __restrict__ row,
                                                   const int* __restrict__ flags, int e_cnt, int n,
                                                   int* __restrict__ cnt) {
    int imode = flags[1];
    int e = blockIdx.x * 256 + threadIdx.x;
    if (e >= e_cnt) return;
    int r = fetch_idx(row, e, imode);
    if ((unsigned)r < (unsigned)n) atomicAdd(&cnt[r], 1);
}

__global__ __launch_bounds__(256) void scan_partial(const int* __restrict__ cnt, int n,
                                                    int* __restrict__ bsum) {
    __shared__ int red[256];
    int b = blockIdx.x, t = threadIdx.x;
    int base = b * 2048;
    int s = 0;
    for (int i = t; i < 2048; i += 256) {
        int idx = base + i;
        if (idx < n) s += cnt[idx];
    }
    red[t] = s;
    __syncthreads();
    for (int off = 128; off > 0; off >>= 1) {
        if (t < off) red[t] += red[t + off];
        __syncthreads();
    }
    if (t == 0) bsum[b] = red[0];
}

__global__ __launch_bounds__(1024) void scan_bsum(int* __restrict__ bsum, int nb,
                                                  int* __restrict__ total) {
    __shared__ int sh[1024];
    int t = threadIdx.x;
    int v = (t < nb) ? bsum[t] : 0;
    sh[t] = v;
    __syncthreads();
    for (int off = 1; off < 1024; off <<= 1) {
        int u = (t >= off) ? sh[t - off] : 0;
        __syncthreads();
        sh[t] += u;
        __syncthreads();
    }
    if (t < nb) bsum[t] = sh[t] - v;
    if (t == 1023) *total = sh[1023];
}

__global__ __launch_bounds__(256) void scan_write(const int* __restrict__ cnt, int n,
                                                  const int* __restrict__ bsum,
                                                  const int* __restrict__ total,
                                                  int* __restrict__ row_ptr,
                                                  int* __restrict__ cursor) {
    __shared__ int red[256];
    int b = blockIdx.x, t = threadIdx.x;
    int idx0 = b * 2048 + t * 8;
    int v[8];
    int s = 0;
#pragma unroll
    for (int j = 0; j < 8; j++) {
        int idx = idx0 + j;
        v[j] = (idx < n) ? cnt[idx] : 0;
        s += v[j];
    }
    red[t] = s;
    __syncthreads();
    for (int off = 1; off < 256; off <<= 1) {
        int u = (t >= off) ? red[t - off] : 0;
        __syncthreads();
        red[t] += u;
        __syncthreads();
    }
    int run = bsum[b] + red[t] - s;
#pragma unroll
    for (int j = 0; j < 8; j++) {
        int idx = idx0 + j;
        if (idx < n) {
            row_ptr[idx] = run;
            cursor[idx] = run;
            run += v[j];
        }
    }
    if (b == 0 && t == 0) row_ptr[n] = *total;
}

__global__ __launch_bounds__(256) void scatter_kernel(const void* __restrict__ row,
                                                      const void* __restrict__ col,
                                                      const float* __restrict__ vals,
                                                      const int* __restrict__ flags, int e_cnt,
                                                      int n, int* __restrict__ cursor,
                                                      int* __restrict__ col_s,
                                                      float* __restrict__ val_s) {
    int imode = flags[1];
    int e = blockIdx.x * 256 + threadIdx.x;
    if (e >= e_cnt) return;
    int r = fetch_idx(row, e, imode);
    if ((unsigned)r >= (unsigned)n) return;
    int c = fetch_idx(col, e, imode);
    if ((unsigned)c >= (unsigned)n) c = 0;
    int pos = atomicAdd(&cursor[r], 1);
    col_s[pos] = c;
    val_s[pos] = vals[e];
}

// ---------------- SpMM: ax = A @ x  (CSR, one wave per output row) ----------------
// Algebraic restructure: A @ (x W^T) == (A @ x) W^T, so the E-edge sweep runs
// ONCE per pass instead of once per layer. Dual variant produces masked+full
// outputs from a single gather sweep (mask is wave-uniform per edge).

__global__ __launch_bounds__(256) void spmm_dual(const float* __restrict__ X,
                                                 const int* __restrict__ row_ptr,
                                                 const int* __restrict__ col_s,
                                                 const float* __restrict__ val_s,
                                                 const unsigned char* __restrict__ mask, int n,
                                                 float* __restrict__ ax_m,
                                                 float* __restrict__ ax_f) {
    int gid = blockIdx.x * 256 + threadIdx.x;
    int r = gid >> 6, lane = gid & 63;
    if (r >= n) return;
    int s = row_ptr[r], e = row_ptr[r + 1];
    float af0 = 0.f, af1 = 0.f, am0 = 0.f, am1 = 0.f;
    int i = s;
    for (; i + 1 < e; i += 2) {
        int c0 = col_s[i], c1 = col_s[i + 1];
        float v0 = val_s[i], v1 = val_s[i + 1];
        float f0 = X[(size_t)c0 * 64 + lane];
        float f1 = X[(size_t)c1 * 64 + lane];
        af0 = fmaf(v0, f0, af0);
        af1 = fmaf(v1, f1, af1);
        float w0 = mask[c0] ? 0.f : v0;
        float w1 = mask[c1] ? 0.f : v1;
        am0 = fmaf(w0, f0, am0);
        am1 = fmaf(w1, f1, am1);
    }
    if (i < e) {
        int c = col_s[i];
        float v = val_s[i];
        float f = X[(size_t)c * 64 + lane];
        af0 = fmaf(v, f, af0);
        am0 = fmaf(mask[c] ? 0.f : v, f, am0);
    }
    ax_f[(size_t)r * 64 + lane] = af0 + af1;
    ax_m[(size_t)r * 64 + lane] = am0 + am1;
}

// Single-output masked SpMM; masked columns SKIP the gather (wave-uniform branch,
// ~50% of edges -> halves gather traffic).
__global__ __launch_bounds__(256) void spmm_one(const float* __restrict__ X,
                                                const int* __restrict__ row_ptr,
                                                const int* __restrict__ col_s,
                                                const float* __restrict__ val_s,
                                                const unsigned char* __restrict__ mask, int n,
                                                float* __restrict__ ax) {
    int gid = blockIdx.x * 256 + threadIdx.x;
    int r = gid >> 6, lane = gid & 63;
    if (r >= n) return;
    int s = row_ptr[r], e = row_ptr[r + 1];
    float a0 = 0.f, a1 = 0.f;
    int i = s;
    for (; i + 1 < e; i += 2) {
        int c0 = col_s[i], c1 = col_s[i + 1];
        if (!mask[c0]) a0 = fmaf(val_s[i], X[(size_t)c0 * 64 + lane], a0);
        if (!mask[c1]) a1 = fmaf(val_s[i + 1], X[(size_t)c1 * 64 + lane], a1);
    }
    if (i < e) {
        int c = col_s[i];
        if (!mask[c]) a0 = fmaf(val_s[i], X[(size_t)c * 64 + lane], a0);
    }
    ax[(size_t)r * 64 + lane] = a0 + a1;
}

// ---------------- MFMA dense GEMM + fused bias + PReLU ----------------
// embeds[p][r][c] = PReLU( sum_h ax[r][h] * Wg[p][c][h] + b[p][c] )
// 16x16x32 bf16 MFMA, bf16x3 split (8 terms incl lo*lo for headroom). Wave wv
// owns col-tile [wv*16,wv*16+16); W fragments preloaded, reused across row
// tiles (grid-stride). C/D layout: col=lane&15, row=(lane>>4)*4+reg [m89/m91].

template <int PP>
__global__ __launch_bounds__(256) void gemm_bias_prelu(const float* __restrict__ X,
                                                       const float* __restrict__ Wg,
                                                       const float* __restrict__ b,
                                                       const float* __restrict__ a,
                                                       float* __restrict__ Y, int n) {
    int t = threadIdx.x;
    int wv = t >> 6, lane = t & 63, nl = lane & 15, q = lane >> 4;
    int colg = wv * 16 + nl;
    bf16x8 bhi[PP][2], blo[PP][2];
    float bias[PP], slope[PP];
#pragma unroll
    for (int p = 0; p < PP; p++) {
#pragma unroll
        for (int kk = 0; kk < 2; kk++)
            split8(Wg + p * 4096 + colg * 64 + kk * 32 + q * 8, true, bhi[p][kk], blo[p][kk]);
        bias[p] = b[p * 64 + colg];
        slope[p] = a[p];
    }
    int ntiles = (n + 15) >> 4;
    for (int rt = blockIdx.x; rt < ntiles; rt += gridDim.x) {
        int rowi = rt * 16 + nl;
        bool ok = rowi < n;
        bf16x8 ah[2], al[2];
#pragma unroll
        for (int kk = 0; kk < 2; kk++)
            split8(X + (size_t)rowi * 64 + kk * 32 + q * 8, ok, ah[kk], al[kk]);
#pragma unroll
        for (int p = 0; p < PP; p++) {
            f32x4 acc = {0.f, 0.f, 0.f, 0.f};
            acc = __builtin_amdgcn_mfma_f32_16x16x32_bf16(ah[0], bhi[p][0], acc, 0, 0, 0);
            acc = __builtin_amdgcn_mfma_f32_16x16x32_bf16(ah[1], bhi[p][1], acc, 0, 0, 0);
            acc = __builtin_amdgcn_mfma_f32_16x16x32_bf16(al[0], bhi[p][0], acc, 0, 0, 0);
            acc = __builtin_amdgcn_mfma_f32_16x16x32_bf16(al[1], bhi[p][1], acc, 0, 0, 0);
            acc = __builtin_amdgcn_mfma_f32_16x16x32_bf16(ah[0], blo[p][0], acc, 0, 0, 0);
            acc = __builtin_amdgcn_mfma_f32_16x16x32_bf16(ah[1], blo[p][1], acc, 0, 0, 0);
            acc = __builtin_amdgcn_mfma_f32_16x16x32_bf16(al[0], blo[p][0], acc, 0, 0, 0);
            acc = __builtin_amdgcn_mfma_f32_16x16x32_bf16(al[1], blo[p][1], acc, 0, 0, 0);
#pragma unroll
            for (int i = 0; i < 4; i++) {
                int r = rt * 16 + q * 4 + i;
                if (r < n) {
                    float o = acc[i] + bias[p];
                    Y[(size_t)p * n * 64 + (size_t)r * 64 + colg] =
                        (o > 0.f) ? o : slope[p] * o;
                }
            }
        }
    }
}

// ---------------- attention: s_sums[p][k] = sum_n tanh( embed_p[n] . fc_w[k] + fc_b[k] ) ------

__global__ __launch_bounds__(256) void fc_tanh_mfma(const float* __restrict__ embeds,
                                                    const float* __restrict__ fcw,
                                                    const float* __restrict__ fcb, int n,
                                                    float* __restrict__ s_sums) {
    int p = blockIdx.y;
    const float* X = embeds + (size_t)p * n * 64;
    int t = threadIdx.x;
    int wv = t >> 6, lane = t & 63, nl = lane & 15, q = lane >> 4;
    int colg = wv * 16 + nl;
    bf16x8 bhi[2], blo[2];
#pragma unroll
    for (int kk = 0; kk < 2; kk++)
        split8(fcw + colg * 64 + kk * 32 + q * 8, true, bhi[kk], blo[kk]);
    float bias = fcb[colg];
    float ssum = 0.f;
    int ntiles = (n + 15) >> 4;
    for (int rt = blockIdx.x; rt < ntiles; rt += gridDim.x) {
        int rowi = rt * 16 + nl;
        bool ok = rowi < n;
        bf16x8 ah[2], al[2];
#pragma unroll
        for (int kk = 0; kk < 2; kk++)
            split8(X + (size_t)rowi * 64 + kk * 32 + q * 8, ok, ah[kk], al[kk]);
        f32x4 acc = {0.f, 0.f, 0.f, 0.f};
        acc = __builtin_amdgcn_mfma_f32_16x16x32_bf16(ah[0], bhi[0], acc, 0, 0, 0);
        acc = __builtin_amdgcn_mfma_f32_16x16x32_bf16(ah[1], bhi[1], acc, 0, 0, 0);
        acc = __builtin_amdgcn_mfma_f32_16x16x32_bf16(al[0], bhi[0], acc, 0, 0, 0);
        acc = __builtin_amdgcn_mfma_f32_16x16x32_bf16(al[1], bhi[1], acc, 0, 0, 0);
        acc = __builtin_amdgcn_mfma_f32_16x16x32_bf16(ah[0], blo[0], acc, 0, 0, 0);
        acc = __builtin_amdgcn_mfma_f32_16x16x32_bf16(ah[1], blo[1], acc, 0, 0, 0);
#pragma unroll
        for (int i = 0; i < 4; i++) {
            int r = rt * 16 + q * 4 + i;
            if (r < n) ssum += tanhf(acc[i] + bias);
        }
    }
    ssum += __shfl_xor(ssum, 16);
    ssum += __shfl_xor(ssum, 32);
    if (q == 0) atomicAdd(&s_sums[p * 64 + colg], ssum);
}

__global__ __launch_bounds__(64) void compute_beta(const float* __restrict__ s_sums,
                                                   const float* __restrict__ att, int n, int P,
                                                   float* __restrict__ beta) {
    int lane = threadIdx.x;
    float av = att[lane];
    float l[8];
    for (int p = 0; p < P; p++) l[p] = s_sums[p * 64 + lane] * av;
#pragma unroll
    for (int off = 32; off > 0; off >>= 1)
        for (int p = 0; p < 8; p++)
            if (p < P) l[p] += __shfl_down(l[p], off);
    if (lane == 0) {
        const float inv = 1.0f / (float)n;
        float m = -1e30f;
        for (int p = 0; p < P; p++) {
            l[p] *= inv;
            m = fmaxf(m, l[p]);
        }
        float s = 0.f;
        for (int p = 0; p < P; p++) {
            l[p] = __expf(l[p] - m);
            s += l[p];
        }
        for (int p = 0; p < P; p++) beta[p] = l[p] / s;
    }
}

// Output dtype FLOAT32 (verified round 5).
__global__ __launch_bounds__(256) void mix_out(const float* __restrict__ embeds,
                                               const float* __restrict__ beta, int n, int P,
                                               float* __restrict__ out) {
    int idx = blockIdx.x * 256 + threadIdx.x;
    size_t base = (size_t)idx * 4;
    size_t tot = (size_t)n * 64;
    if (base >= tot) return;
    float4 o = make_float4(0.f, 0.f, 0.f, 0.f);
    for (int p = 0; p < P; p++) {
        float bp = beta[p];
        float4 x = *(const float4*)(embeds + (size_t)p * tot + base);
        o.x = fmaf(bp, x.x, o.x);
        o.y = fmaf(bp, x.y, o.y);
        o.z = fmaf(bp, x.z, o.z);
        o.w = fmaf(bp, x.w, o.w);
    }
    *(float4*)(out + base) = o;
}

// ---------------- driver ----------------

extern "C" void kernel_launch(void* const* d_in, const int* in_sizes, int n_in,
                              void* d_out, int out_size, void* d_ws, size_t ws_size,
                              hipStream_t stream) {
    const float* h = (const float*)d_in[0];
    const float* W = (const float*)d_in[1];
    const float* b = (const float*)d_in[2];
    const float* a = (const float*)d_in[3];
    const float* fc_w = (const float*)d_in[4];
    const float* fc_b = (const float*)d_in[5];
    const float* att = (const float*)d_in[6];
    const float* adj = (const float*)d_in[7];
    const void* row = d_in[8];
    const void* col = d_in[9];
    const void* mask1 = d_in[10];
    const void* mask2 = d_in[11];
    float* out = (float*)d_out;

    int P = in_sizes[3];
    if (P < 1 || P > 8) P = 3;
    int N = in_sizes[0] / 64;
    int E = in_sizes[7];

    char* w = (char*)d_ws;
    auto alloc = [&](size_t bytes) {
        void* p = (void*)w;
        w += (bytes + 255) & ~(size_t)255;
        return p;
    };
    int* cnt = (int*)alloc((size_t)N * 4);
    int* row_ptr = (int*)alloc((size_t)(N + 1) * 4);
    int* cursor = (int*)alloc((size_t)N * 4);
    int* col_s = (int*)alloc((size_t)E * 4);
    float* val_s = (float*)alloc((size_t)E * 4);
    unsigned char* m1c = (unsigned char*)alloc(N);
    unsigned char* m2c = (unsigned char*)alloc(N);
    float* axm = (float*)alloc((size_t)N * 64 * 4);   // A @ (x * ~mask)
    float* axf = (float*)alloc((size_t)N * 64 * 4);   // A @ x
    float* embeds = (float*)alloc((size_t)P * N * 64 * 4);
    float* s_sums = (float*)alloc(8 * 64 * 4);
    float* beta = (float*)alloc(8 * 4);
    int* flags = (int*)alloc(256);
    int nsb = (N + 2047) / 2048;
    int* bsum = (int*)alloc((size_t)(nsb + 1) * 4);
    int* etotal = (int*)alloc(256);

    int nw_mask = N / 4 > 25000 ? 25000 : N / 4;
    int nw_idx = E / 4 > 25000 ? 25000 : E / 4;
    forensic_kernel<<<1, 256, 0, stream>>>((const unsigned int*)mask1, (const unsigned int*)row,
                                           nw_mask, nw_idx, flags);
    conv_mask_kernel<<<(N + 255) / 256, 256, 0, stream>>>(mask1, flags, N, m1c);
    conv_mask_kernel<<<(N + 255) / 256, 256, 0, stream>>>(mask2, flags, N, m2c);

    hipMemsetAsync(cnt, 0, (size_t)N * 4, stream);
    hist_kernel<<<(E + 255) / 256, 256, 0, stream>>>(row, flags, E, N, cnt);
    scan_partial<<<nsb, 256, 0, stream>>>(cnt, N, bsum);
    scan_bsum<<<1, 1024, 0, stream>>>(bsum, nsb, etotal);
    scan_write<<<nsb, 256, 0, stream>>>(cnt, N, bsum, etotal, row_ptr, cursor);
    scatter_kernel<<<(E + 255) / 256, 256, 0, stream>>>(row, col, adj, flags, E, N, cursor, col_s,
                                                        val_s);

    int spmm_grid = ((size_t)N * 64 + 255) / 256;  // one wave per row
    int mix_grid = ((size_t)N * 64 / 4 + 255) / 256;
    int gemm_blocks = 1024;
    int fc_blocks = 512;

    // tail pipeline: ax -> P dense layers (bias+PReLU fused) -> attention mix
    auto tail = [&](const float* ax, float* dst) {
        if (P == 3) {
            gemm_bias_prelu<3><<<gemm_blocks, 256, 0, stream>>>(ax, W, b, a, embeds, N);
        } else {
            for (int p = 0; p < P; p++)
                gemm_bias_prelu<1><<<gemm_blocks, 256, 0, stream>>>(
                    ax, W + p * 4096, b + p * 64, a + p, embeds + (size_t)p * N * 64, N);
        }
        hipMemsetAsync(s_sums, 0, 8 * 64 * 4, stream);
        fc_tanh_mfma<<<dim3(fc_blocks, P), 256, 0, stream>>>(embeds, fc_w, fc_b, N, s_sums);
        compute_beta<<<1, 64, 0, stream>>>(s_sums, att, N, P, beta);
        mix_out<<<mix_grid, 256, 0, stream>>>(embeds, beta, N, P, dst);
    };

    // pass 0 + 1 share one edge sweep: ax_masked and ax_full from a single gather
    spmm_dual<<<spmm_grid, 256, 0, stream>>>(h, row_ptr, col_s, val_s, m1c, N, axm, axf);
    tail(axm, out);                         // z_mp
    tail(axf, out + (size_t)N * 64);        // z_mp2
    // pass 2 decodes from z_mp (in d_out), masked by mask2 (gather skipped when masked)
    spmm_one<<<spmm_grid, 256, 0, stream>>>(out, row_ptr, col_s, val_s, m2c, N, axm);
    tail(axm, out + (size_t)2 * N * 64);    // x_recon
}

// Round 2
// 708.956 us; speedup vs baseline: 2.1218x; 1.2741x over previous
//
#include <hip/hip_runtime.h>
#include <hip/hip_bf16.h>

typedef __hip_bfloat16 bf16;
typedef __attribute__((ext_vector_type(8))) short bf16x8;  // 8 bf16 in 4 VGPRs
typedef __attribute__((ext_vector_type(4))) float f32x4;

// ---------------- bf16 split helpers (Ootomo bf16x3 scheme) ----------------

__device__ __forceinline__ short f2bf(float x) {  // RNE float->bf16 bits
    unsigned u = __float_as_uint(x);
    unsigned r = (u + 0x7FFFu + ((u >> 16) & 1u)) >> 16;
    return (short)r;
}
__device__ __forceinline__ float bf2f(short s) {
    return __uint_as_float(((unsigned)(unsigned short)s) << 16);
}

// Load 8 consecutive floats (16B-aligned), split into hi/lo bf16 fragments.
__device__ __forceinline__ void split8(const float* __restrict__ p, bool ok, bf16x8& hi,
                                       bf16x8& lo) {
    float v[8];
    if (ok) {
        float4 x0 = ((const float4*)p)[0];
        float4 x1 = ((const float4*)p)[1];
        v[0] = x0.x; v[1] = x0.y; v[2] = x0.z; v[3] = x0.w;
        v[4] = x1.x; v[5] = x1.y; v[6] = x1.z; v[7] = x1.w;
    } else {
#pragma unroll
        for (int j = 0; j < 8; j++) v[j] = 0.f;
    }
#pragma unroll
    for (int j = 0; j < 8; j++) {
        short hb = f2bf(v[j]);
        hi[j] = hb;
        lo[j] = f2bf(v[j] - bf2f(hb));
    }
}

__device__ __forceinline__ float fast_tanh(float x) {
    x = fminf(fmaxf(x, -15.f), 15.f);
    float t = __expf(2.f * x);
    return __fdividef(t - 1.f, t + 1.f);
}

__device__ __forceinline__ void fma4(float4& acc, float v, const float4& x) {
    acc.x = fmaf(v, x.x, acc.x);
    acc.y = fmaf(v, x.y, acc.y);
    acc.z = fmaf(v, x.z, acc.z);
    acc.w = fmaf(v, x.w, acc.w);
}

__device__ __forceinline__ void red4(float4& a) {
    a.x += __shfl_xor(a.x, 16); a.y += __shfl_xor(a.y, 16);
    a.z += __shfl_xor(a.z, 16); a.w += __shfl_xor(a.w, 16);
    a.x += __shfl_xor(a.x, 32); a.y += __shfl_xor(a.y, 32);
    a.z += __shfl_xor(a.z, 32); a.w += __shfl_xor(a.w, 32);
}

// ---------------- dtype forensics (masks / indices) ----------------
// modes: 0=u8/bool, 1=int32, 2=float32, 3=int64, 4=float64
__global__ __launch_bounds__(256) void forensic_kernel(const unsigned int* __restrict__ mask_w,
                                                       const unsigned int* __restrict__ idx_w,
                                                       int nw_mask, int nw_idx,
                                                       int* __restrict__ flags) {
    __shared__ int sm[6];
    int t = threadIdx.x;
    if (t < 6) sm[t] = 0;
    __syncthreads();
    int m_gt1 = 0, m_f32 = 0, m_f64 = 0, m_oddnz = 0, i_hi = 0, i_oddnz = 0;
    for (int i = t; i < nw_mask; i += 256) {
        unsigned int w = mask_w[i];
        if (w > 1u && w != 0x3F800000u && w != 0x3FF00000u) m_gt1++;
        if (w == 0x3F800000u) m_f32++;
        if ((i & 1) && w == 0x3FF00000u) m_f64++;
        if ((i & 1) && w != 0u) m_oddnz++;
    }
    for (int i = t; i < nw_idx; i += 256) {
        unsigned int v = idx_w[i];
        if (v >= 0x20000000u) i_hi++;
        if ((i & 1) && v != 0u) i_oddnz++;
    }
    atomicAdd(&sm[0], m_gt1);
    atomicAdd(&sm[1], m_f32);
    atomicAdd(&sm[2], m_f64);
    atomicAdd(&sm[3], m_oddnz);
    atomicAdd(&sm[4], i_hi);
    atomicAdd(&sm[5], i_oddnz);
    __syncthreads();
    if (t == 0) {
        int mmode;
        if (sm[1] > 50) mmode = 2;
        else if (sm[2] > 50) mmode = 4;
        else if (sm[0] > 50) mmode = 0;
        else if (sm[3] > 50) mmode = 1;
        else mmode = 3;
        int imode;
        if (sm[4] > (nw_idx * 3) / 4) imode = 2;
        else if (sm[4] > nw_idx / 4) imode = 4;
        else if (sm[5] > 50) imode = 1;
        else imode = 3;
        flags[0] = mmode;
        flags[1] = imode;
    }
}

__device__ __forceinline__ int fetch_idx(const void* p, int e, int mode) {
    switch (mode) {
        case 1: return ((const int*)p)[e];
        case 3: return (int)(((const long long*)p)[e]);
        case 2: return (int)(((const float*)p)[e]);
        default: return (int)(((const double*)p)[e]);
    }
}

__global__ __launch_bounds__(256) void conv_mask_kernel(const void* __restrict__ m,
                                                        const int* __restrict__ flags, int n,
                                                        unsigned char* __restrict__ out) {
    int mode = flags[0];
    int i = blockIdx.x * 256 + threadIdx.x;
    if (i >= n) return;
    bool v;
    switch (mode) {
        case 0: v = ((const unsigned char*)m)[i] != 0; break;
        case 1: v = ((const int*)m)[i] != 0; break;
        case 2: v = ((const float*)m)[i] != 0.f; break;
        case 3: v = ((const long long*)m)[i] != 0; break;
        default: v = ((const double*)m)[i] != 0.0; break;
    }
    out[i] = v ? 1 : 0;
}

// ---------------- CSR build ----------------

__global__ __launch_bounds__(256) void hist_kernel(const void* __restrict__ row,
                                                   const int* __restrict__ flags, int e_cnt, int n,
                                                   int* __restrict__ cnt) {
    int imode = flags[1];
    int e = blockIdx.x * 256 + threadIdx.x;
    if (e >= e_cnt) return;
    int r = fetch_idx(row, e, imode);
    if ((unsigned)r < (unsigned)n) atomicAdd(&cnt[r], 1);
}

__global__ __launch_bounds__(256) void scan_partial(const int* __restrict__ cnt, int n,
                                                    int* __restrict__ bsum) {
    __shared__ int red[256];
    int b = blockIdx.x, t = threadIdx.x;
    int base = b * 2048;
    int s = 0;
    for (int i = t; i < 2048; i += 256) {
        int idx = base + i;
        if (idx < n) s += cnt[idx];
    }
    red[t] = s;
    __syncthreads();
    for (int off = 128; off > 0; off >>= 1) {
        if (t < off) red[t] += red[t + off];
        __syncthreads();
    }
    if (t == 0) bsum[b] = red[0];
}

__global__ __launch_bounds__(1024) void scan_bsum(int* __restrict__ bsum, int nb,
                                                  int* __restrict__ total) {
    __shared__ int sh[1024];
    int t = threadIdx.x;
    int v = (t < nb) ? bsum[t] : 0;
    sh[t] = v;
    __syncthreads();
    for (int off = 1; off < 1024; off <<= 1) {
        int u = (t >= off) ? sh[t - off] : 0;
        __syncthreads();
        sh[t] += u;
        __syncthreads();
    }
    if (t < nb) bsum[t] = sh[t] - v;
    if (t == 1023) *total = sh[1023];
}

__global__ __launch_bounds__(256) void scan_write(const int* __restrict__ cnt, int n,
                                                  const int* __restrict__ bsum,
                                                  const int* __restrict__ total,
                                                  int* __restrict__ row_ptr,
                                                  int* __restrict__ cursor) {
    __shared__ int red[256];
    int b = blockIdx.x, t = threadIdx.x;
    int idx0 = b * 2048 + t * 8;
    int v[8];
    int s = 0;
#pragma unroll
    for (int j = 0; j < 8; j++) {
        int idx = idx0 + j;
        v[j] = (idx < n) ? cnt[idx] : 0;
        s += v[j];
    }
    red[t] = s;
    __syncthreads();
    for (int off = 1; off < 256; off <<= 1) {
        int u = (t >= off) ? red[t - off] : 0;
        __syncthreads();
        red[t] += u;
        __syncthreads();
    }
    int run = bsum[b] + red[t] - s;
#pragma unroll
    for (int j = 0; j < 8; j++) {
        int idx = idx0 + j;
        if (idx < n) {
            row_ptr[idx] = run;
            cursor[idx] = run;
            run += v[j];
        }
    }
    if (b == 0 && t == 0) row_ptr[n] = *total;
}

__global__ __launch_bounds__(256) void scatter_kernel(const void* __restrict__ row,
                                                      const void* __restrict__ col,
                                                      const float* __restrict__ vals,
                                                      const int* __restrict__ flags, int e_cnt,
                                                      int n, int* __restrict__ cursor,
                                                      int* __restrict__ col_s,
                                                      float* __restrict__ val_s) {
    int imode = flags[1];
    int e = blockIdx.x * 256 + threadIdx.x;
    if (e >= e_cnt) return;
    int r = fetch_idx(row, e, imode);
    if ((unsigned)r >= (unsigned)n) return;
    int c = fetch_idx(col, e, imode);
    if ((unsigned)c >= (unsigned)n) c = 0;
    int pos = atomicAdd(&cursor[r], 1);
    col_s[pos] = c;
    val_s[pos] = vals[e];
}

// ---------------- SpMM: ax = A @ x  (CSR, one wave per row) ----------------
// Latency-bound fix (round 1 counters: HBM 10%, VALU 19%): preload up to 64
// (col,val) per row into registers (1/lane), shfl-broadcast -> no load-to-
// address chain. 4 x 16-lane groups each gather a DIFFERENT edge as float4
// (16 lanes x 16B = 256B row), 2-deep unrolled = 8 gathers in flight/wave.

__global__ __launch_bounds__(256) void spmm_dual(const float* __restrict__ X,
                                                 const int* __restrict__ row_ptr,
                                                 const int* __restrict__ col_s,
                                                 const float* __restrict__ val_s,
                                                 const unsigned char* __restrict__ mask, int n,
                                                 float* __restrict__ ax_m,
                                                 float* __restrict__ ax_f) {
    int gid = blockIdx.x * 256 + threadIdx.x;
    int r = gid >> 6;
    if (r >= n) return;
    int lane = threadIdx.x & 63;
    int g = lane >> 4, sub = lane & 15;
    int s = row_ptr[r], e = row_ptr[r + 1];
    int cnt = e - s;
    int myc = 0;
    float myvf = 0.f, myvm = 0.f;
    if (lane < cnt) {
        myc = col_s[s + lane];
        float v = val_s[s + lane];
        myvf = v;
        myvm = mask[myc] ? 0.f : v;
    }
    int cmain = cnt > 64 ? 64 : cnt;
    float4 fA = {0, 0, 0, 0}, fB = {0, 0, 0, 0}, mA = {0, 0, 0, 0}, mB = {0, 0, 0, 0};
    for (int i = 0; i < cmain; i += 8) {
        int iA = i + g, iB = i + 4 + g;
        int cA = __shfl(myc, iA), cB = __shfl(myc, iB);
        float vfA = __shfl(myvf, iA), vfB = __shfl(myvf, iB);
        float vmA = __shfl(myvm, iA), vmB = __shfl(myvm, iB);
        if (iA < cmain) {
            float4 x = *(const float4*)(X + (size_t)cA * 64 + sub * 4);
            fma4(fA, vfA, x);
            fma4(mA, vmA, x);
        }
        if (iB < cmain) {
            float4 x = *(const float4*)(X + (size_t)cB * 64 + sub * 4);
            fma4(fB, vfB, x);
            fma4(mB, vmB, x);
        }
    }
    for (int i = 64 + g; i < cnt; i += 4) {  // rare overflow rows
        int c = col_s[s + i];
        float v = val_s[s + i];
        float vm = mask[c] ? 0.f : v;
        float4 x = *(const float4*)(X + (size_t)c * 64 + sub * 4);
        fma4(fA, v, x);
        fma4(mA, vm, x);
    }
    fA.x += fB.x; fA.y += fB.y; fA.z += fB.z; fA.w += fB.w;
    mA.x += mB.x; mA.y += mB.y; mA.z += mB.z; mA.w += mB.w;
    red4(fA);
    red4(mA);
    if (g == 0) {
        *(float4*)(ax_f + (size_t)r * 64 + sub * 4) = fA;
        *(float4*)(ax_m + (size_t)r * 64 + sub * 4) = mA;
    }
}

// Single-output masked SpMM; masked edges skip the gather entirely
// (group-uniform predicate -> no memory transaction issued).
__global__ __launch_bounds__(256) void spmm_one(const float* __restrict__ X,
                                                const int* __restrict__ row_ptr,
                                                const int* __restrict__ col_s,
                                                const float* __restrict__ val_s,
                                                const unsigned char* __restrict__ mask, int n,
                                                float* __restrict__ ax) {
    int gid = blockIdx.x * 256 + threadIdx.x;
    int r = gid >> 6;
    if (r >= n) return;
    int lane = threadIdx.x & 63;
    int g = lane >> 4, sub = lane & 15;
    int s = row_ptr[r], e = row_ptr[r + 1];
    int cnt = e - s;
    int myc = 0;
    float myv = 0.f;
    if (lane < cnt) {
        myc = col_s[s + lane];
        float v = val_s[s + lane];
        myv = mask[myc] ? 0.f : v;
    }
    int cmain = cnt > 64 ? 64 : cnt;
    float4 aA = {0, 0, 0, 0}, aB = {0, 0, 0, 0};
    for (int i = 0; i < cmain; i += 8) {
        int iA = i + g, iB = i + 4 + g;
        int cA = __shfl(myc, iA), cB = __shfl(myc, iB);
        float vA = __shfl(myv, iA), vB = __shfl(myv, iB);
        if (iA < cmain && vA != 0.f) {
            float4 x = *(const float4*)(X + (size_t)cA * 64 + sub * 4);
            fma4(aA, vA, x);
        }
        if (iB < cmain && vB != 0.f) {
            float4 x = *(const float4*)(X + (size_t)cB * 64 + sub * 4);
            fma4(aB, vB, x);
        }
    }
    for (int i = 64 + g; i < cnt; i += 4) {
        int c = col_s[s + i];
        if (mask[c]) continue;
        float v = val_s[s + i];
        float4 x = *(const float4*)(X + (size_t)c * 64 + sub * 4);
        fma4(aA, v, x);
    }
    aA.x += aB.x; aA.y += aB.y; aA.z += aB.z; aA.w += aB.w;
    red4(aA);
    if (g == 0) *(float4*)(ax + (size_t)r * 64 + sub * 4) = aA;
}

// ---------------- fused kernel A: embed GEMM (bias+PReLU) -> LDS -> fc GEMM -> tanh-sum -----
// Eliminates the embeds materialization (round-1 tails = 281MB traffic/pass).
// embed tile (16 rows x 64 cols, f32, stride 68 -> conflict-free b128 reads)
// lives only in LDS. s_sums[p][k] += sum_rows tanh(fc(embed)).

template <int PP>
__global__ __launch_bounds__(256) void gemm_tanh(const float* __restrict__ X,
                                                 const float* __restrict__ Wg,
                                                 const float* __restrict__ b,
                                                 const float* __restrict__ a,
                                                 const float* __restrict__ fcw,
                                                 const float* __restrict__ fcb, int n,
                                                 float* __restrict__ s_sums) {
    __shared__ __align__(16) float tile[PP][16][68];
    int t = threadIdx.x;
    int wv = t >> 6, lane = t & 63, nl = lane & 15, q = lane >> 4;
    int colg = wv * 16 + nl;
    bf16x8 whi[PP][2], wlo[PP][2];
    float bias[PP], slope[PP];
#pragma unroll
    for (int p = 0; p < PP; p++) {
#pragma unroll
        for (int kk = 0; kk < 2; kk++)
            split8(Wg + p * 4096 + colg * 64 + kk * 32 + q * 8, true, whi[p][kk], wlo[p][kk]);
        bias[p] = b[p * 64 + colg];
        slope[p] = a[p];
    }
    bf16x8 fhi[2], flo[2];
#pragma unroll
    for (int kk = 0; kk < 2; kk++)
        split8(fcw + colg * 64 + kk * 32 + q * 8, true, fhi[kk], flo[kk]);
    float fbias = fcb[colg];
    float ssum[PP];
#pragma unroll
    for (int p = 0; p < PP; p++) ssum[p] = 0.f;

    int ntiles = (n + 15) >> 4;
    for (int rt = blockIdx.x; rt < ntiles; rt += gridDim.x) {
        int rowi = rt * 16 + nl;
        bool ok = rowi < n;
        bf16x8 ah[2], al[2];
#pragma unroll
        for (int kk = 0; kk < 2; kk++)
            split8(X + (size_t)rowi * 64 + kk * 32 + q * 8, ok, ah[kk], al[kk]);
#pragma unroll
        for (int p = 0; p < PP; p++) {
            f32x4 acc = {0.f, 0.f, 0.f, 0.f};
            acc = __builtin_amdgcn_mfma_f32_16x16x32_bf16(ah[0], whi[p][0], acc, 0, 0, 0);
            acc = __builtin_amdgcn_mfma_f32_16x16x32_bf16(ah[1], whi[p][1], acc, 0, 0, 0);
            acc = __builtin_amdgcn_mfma_f32_16x16x32_bf16(al[0], whi[p][0], acc, 0, 0, 0);
            acc = __builtin_amdgcn_mfma_f32_16x16x32_bf16(al[1], whi[p][1], acc, 0, 0, 0);
            acc = __builtin_amdgcn_mfma_f32_16x16x32_bf16(ah[0], wlo[p][0], acc, 0, 0, 0);
            acc = __builtin_amdgcn_mfma_f32_16x16x32_bf16(ah[1], wlo[p][1], acc, 0, 0, 0);
            acc = __builtin_amdgcn_mfma_f32_16x16x32_bf16(al[0], wlo[p][0], acc, 0, 0, 0);
            acc = __builtin_amdgcn_mfma_f32_16x16x32_bf16(al[1], wlo[p][1], acc, 0, 0, 0);
#pragma unroll
            for (int i = 0; i < 4; i++) {
                float o = acc[i] + bias[p];
                tile[p][q * 4 + i][colg] = (o > 0.f) ? o : slope[p] * o;
            }
        }
        __syncthreads();
#pragma unroll
        for (int p = 0; p < PP; p++) {
            bf16x8 eh[2], el[2];
#pragma unroll
            for (int kk = 0; kk < 2; kk++)
                split8(&tile[p][nl][kk * 32 + q * 8], true, eh[kk], el[kk]);
            f32x4 acc = {0.f, 0.f, 0.f, 0.f};
            acc = __builtin_amdgcn_mfma_f32_16x16x32_bf16(eh[0], fhi[0], acc, 0, 0, 0);
            acc = __builtin_amdgcn_mfma_f32_16x16x32_bf16(eh[1], fhi[1], acc, 0, 0, 0);
            acc = __builtin_amdgcn_mfma_f32_16x16x32_bf16(el[0], fhi[0], acc, 0, 0, 0);
            acc = __builtin_amdgcn_mfma_f32_16x16x32_bf16(el[1], fhi[1], acc, 0, 0, 0);
            acc = __builtin_amdgcn_mfma_f32_16x16x32_bf16(eh[0], flo[0], acc, 0, 0, 0);
            acc = __builtin_amdgcn_mfma_f32_16x16x32_bf16(eh[1], flo[1], acc, 0, 0, 0);
#pragma unroll
            for (int i = 0; i < 4; i++) {
                int r = rt * 16 + q * 4 + i;
                if (r < n) ssum[p] += fast_tanh(acc[i] + fbias);
            }
        }
        __syncthreads();
    }
#pragma unroll
    for (int p = 0; p < PP; p++) {
        float s = ssum[p];
        s += __shfl_xor(s, 16);
        s += __shfl_xor(s, 32);
        if (q == 0) atomicAdd(&s_sums[p * 64 + colg], s);
    }
}

// ---------------- fused kernel B: recompute embed GEMM, mix with beta, write out -----------

template <int PP>
__global__ __launch_bounds__(256) void gemm_mix(const float* __restrict__ X,
                                                const float* __restrict__ Wg,
                                                const float* __restrict__ b,
                                                const float* __restrict__ a,
                                                const float* __restrict__ beta, int n,
                                                float* __restrict__ out, int accum) {
    int t = threadIdx.x;
    int wv = t >> 6, lane = t & 63, nl = lane & 15, q = lane >> 4;
    int colg = wv * 16 + nl;
    bf16x8 whi[PP][2], wlo[PP][2];
    float bias[PP], slope[PP], bet[PP];
#pragma unroll
    for (int p = 0; p < PP; p++) {
#pragma unroll
        for (int kk = 0; kk < 2; kk++)
            split8(Wg + p * 4096 + colg * 64 + kk * 32 + q * 8, true, whi[p][kk], wlo[p][kk]);
        bias[p] = b[p * 64 + colg];
        slope[p] = a[p];
        bet[p] = beta[p];
    }
    int ntiles = (n + 15) >> 4;
    for (int rt = blockIdx.x; rt < ntiles; rt += gridDim.x) {
        int rowi = rt * 16 + nl;
        bool ok = rowi < n;
        bf16x8 ah[2], al[2];
#pragma unroll
        for (int kk = 0; kk < 2; kk++)
            split8(X + (size_t)rowi * 64 + kk * 32 + q * 8, ok, ah[kk], al[kk]);
        float mix[4] = {0.f, 0.f, 0.f, 0.f};
#pragma unroll
        for (int p = 0; p < PP; p++) {
            f32x4 acc = {0.f, 0.f, 0.f, 0.f};
            acc = __builtin_amdgcn_mfma_f32_16x16x32_bf16(ah[0], whi[p][0], acc, 0, 0, 0);
            acc = __builtin_amdgcn_mfma_f32_16x16x32_bf16(ah[1], whi[p][1], acc, 0, 0, 0);
            acc = __builtin_amdgcn_mfma_f32_16x16x32_bf16(al[0], whi[p][0], acc, 0, 0, 0);
            acc = __builtin_amdgcn_mfma_f32_16x16x32_bf16(al[1], whi[p][1], acc, 0, 0, 0);
            acc = __builtin_amdgcn_mfma_f32_16x16x32_bf16(ah[0], wlo[p][0], acc, 0, 0, 0);
            acc = __builtin_amdgcn_mfma_f32_16x16x32_bf16(ah[1], wlo[p][1], acc, 0, 0, 0);
            acc = __builtin_amdgcn_mfma_f32_16x16x32_bf16(al[0], wlo[p][0], acc, 0, 0, 0);
            acc = __builtin_amdgcn_mfma_f32_16x16x32_bf16(al[1], wlo[p][1], acc, 0, 0, 0);
#pragma unroll
            for (int i = 0; i < 4; i++) {
                float o = acc[i] + bias[p];
                o = (o > 0.f) ? o : slope[p] * o;
                mix[i] = fmaf(bet[p], o, mix[i]);
            }
        }
#pragma unroll
        for (int i = 0; i < 4; i++) {
            int r = rt * 16 + q * 4 + i;
            if (r < n) {
                size_t idx = (size_t)r * 64 + colg;
                out[idx] = accum ? (out[idx] + mix[i]) : mix[i];
            }
        }
    }
}

__global__ __launch_bounds__(64) void compute_beta(const float* __restrict__ s_sums,
                                                   const float* __restrict__ att, int n, int P,
                                                   float* __restrict__ beta) {
    int lane = threadIdx.x;
    float av = att[lane];
    float l[8];
    for (int p = 0; p < P; p++) l[p] = s_sums[p * 64 + lane] * av;
#pragma unroll
    for (int off = 32; off > 0; off >>= 1)
        for (int p = 0; p < 8; p++)
            if (p < P) l[p] += __shfl_down(l[p], off);
    if (lane == 0) {
        const float inv = 1.0f / (float)n;
        float m = -1e30f;
        for (int p = 0; p < P; p++) {
            l[p] *= inv;
            m = fmaxf(m, l[p]);
        }
        float s = 0.f;
        for (int p = 0; p < P; p++) {
            l[p] = __expf(l[p] - m);
            s += l[p];
        }
        for (int p = 0; p < P; p++) beta[p] = l[p] / s;
    }
}

// ---------------- driver ----------------

extern "C" void kernel_launch(void* const* d_in, const int* in_sizes, int n_in,
                              void* d_out, int out_size, void* d_ws, size_t ws_size,
                              hipStream_t stream) {
    const float* h = (const float*)d_in[0];
    const float* W = (const float*)d_in[1];
    const float* b = (const float*)d_in[2];
    const float* a = (const float*)d_in[3];
    const float* fc_w = (const float*)d_in[4];
    const float* fc_b = (const float*)d_in[5];
    const float* att = (const float*)d_in[6];
    const float* adj = (const float*)d_in[7];
    const void* row = d_in[8];
    const void* col = d_in[9];
    const void* mask1 = d_in[10];
    const void* mask2 = d_in[11];
    float* out = (float*)d_out;

    int P = in_sizes[3];
    if (P < 1 || P > 8) P = 3;
    int N = in_sizes[0] / 64;
    int E = in_sizes[7];

    char* w = (char*)d_ws;
    auto alloc = [&](size_t bytes) {
        void* p = (void*)w;
        w += (bytes + 255) & ~(size_t)255;
        return p;
    };
    int* cnt = (int*)alloc((size_t)N * 4);
    int* row_ptr = (int*)alloc((size_t)(N + 1) * 4);
    int* cursor = (int*)alloc((size_t)N * 4);
    int* col_s = (int*)alloc((size_t)E * 4);
    float* val_s = (float*)alloc((size_t)E * 4);
    unsigned char* m1c = (unsigned char*)alloc(N);
    unsigned char* m2c = (unsigned char*)alloc(N);
    float* axm = (float*)alloc((size_t)N * 64 * 4);  // A @ (x * ~mask)
    float* axf = (float*)alloc((size_t)N * 64 * 4);  // A @ x
    float* s_sums = (float*)alloc(8 * 64 * 4);
    float* beta = (float*)alloc(8 * 4);
    int* flags = (int*)alloc(256);
    int nsb = (N + 2047) / 2048;
    int* bsum = (int*)alloc((size_t)(nsb + 1) * 4);
    int* etotal = (int*)alloc(256);

    int nw_mask = N / 4 > 25000 ? 25000 : N / 4;
    int nw_idx = E / 4 > 25000 ? 25000 : E / 4;
    forensic_kernel<<<1, 256, 0, stream>>>((const unsigned int*)mask1, (const unsigned int*)row,
                                           nw_mask, nw_idx, flags);
    conv_mask_kernel<<<(N + 255) / 256, 256, 0, stream>>>(mask1, flags, N, m1c);
    conv_mask_kernel<<<(N + 255) / 256, 256, 0, stream>>>(mask2, flags, N, m2c);

    hipMemsetAsync(cnt, 0, (size_t)N * 4, stream);
    hist_kernel<<<(E + 255) / 256, 256, 0, stream>>>(row, flags, E, N, cnt);
    scan_partial<<<nsb, 256, 0, stream>>>(cnt, N, bsum);
    scan_bsum<<<1, 1024, 0, stream>>>(bsum, nsb, etotal);
    scan_write<<<nsb, 256, 0, stream>>>(cnt, N, bsum, etotal, row_ptr, cursor);
    scatter_kernel<<<(E + 255) / 256, 256, 0, stream>>>(row, col, adj, flags, E, N, cursor, col_s,
                                                        val_s);

    int spmm_grid = ((size_t)N * 64 + 255) / 256;  // one wave per row
    int gemm_blocks = 1024;

    // tail: ax -> [A: embed GEMM + fc + tanh-sum] -> beta -> [B: recompute + mix]
    auto tail = [&](const float* ax, float* dst) {
        hipMemsetAsync(s_sums, 0, 8 * 64 * 4, stream);
        if (P == 3) {
            gemm_tanh<3><<<gemm_blocks, 256, 0, stream>>>(ax, W, b, a, fc_w, fc_b, N, s_sums);
        } else {
            for (int p = 0; p < P; p++)
                gemm_tanh<1><<<gemm_blocks, 256, 0, stream>>>(ax, W + p * 4096, b + p * 64, a + p,
                                                              fc_w, fc_b, N, s_sums + p * 64);
        }
        compute_beta<<<1, 64, 0, stream>>>(s_sums, att, N, P, beta);
        if (P == 3) {
            gemm_mix<3><<<gemm_blocks, 256, 0, stream>>>(ax, W, b, a, beta, N, dst, 0);
        } else {
            for (int p = 0; p < P; p++)
                gemm_mix<1><<<gemm_blocks, 256, 0, stream>>>(ax, W + p * 4096, b + p * 64, a + p,
                                                             beta + p, N, dst, p != 0);
        }
    };

    // pass 0 + 1 share one edge sweep: ax_masked and ax_full from a single gather
    spmm_dual<<<spmm_grid, 256, 0, stream>>>(h, row_ptr, col_s, val_s, m1c, N, axm, axf);
    tail(axm, out);                       // z_mp
    tail(axf, out + (size_t)N * 64);      // z_mp2
    // pass 2 decodes from z_mp (in d_out), masked by mask2 (gather skipped when masked)
    spmm_one<<<spmm_grid, 256, 0, stream>>>(out, row_ptr, col_s, val_s, m2c, N, axm);
    tail(axm, out + (size_t)2 * N * 64);  // x_recon
}